// Round 9
// baseline (102.955 us; speedup 1.0000x reference)
//
#include <hip/hip_runtime.h>

#define N 256
#define NN 65536

typedef __attribute__((ext_vector_type(8))) __bf16 bf16x8;
typedef __attribute__((ext_vector_type(4))) __bf16 bf16x4v;
typedef __attribute__((ext_vector_type(4))) float f32x4;

// ---- workspace layout (float offsets) ----
#define F_PART   0u         // [512 blocks][128 bl][32 ml] yadj partials (abl dump reuses)
#define F_SPART  2097152u   // [8 mt][256 b][256 n] s_adj partials
#define F_WSC    2621440u   // [256]
#define F_SFULL  2621696u   // [65536]
#define F_YADJ   2687232u   // [65536]
#define WS_FLOATS 2752768u

static __device__ __forceinline__ f32x4 mfma16(bf16x8 a, bf16x8 b, f32x4 c) {
  return __builtin_amdgcn_mfma_f32_16x16x32_bf16(a, b, c, 0, 0, 0);
}
static __device__ __forceinline__ bf16x4v pack4(float4 v) {
  bf16x4v r;
  r[0] = (__bf16)v.x; r[1] = (__bf16)v.y; r[2] = (__bf16)v.z; r[3] = (__bf16)v.w;
  return r;
}
static __device__ __forceinline__ bf16x8 pack8(float4 a, float4 b) {
  bf16x8 r;
  r[0] = (__bf16)a.x; r[1] = (__bf16)a.y; r[2] = (__bf16)a.z; r[3] = (__bf16)a.w;
  r[4] = (__bf16)b.x; r[5] = (__bf16)b.y; r[6] = (__bf16)b.z; r[7] = (__bf16)b.w;
  return r;
}

#define BARL()                                                            \
  asm volatile("s_waitcnt lgkmcnt(0)" ::: "memory");                      \
  __builtin_amdgcn_s_barrier();                                           \
  __builtin_amdgcn_sched_barrier(0);

// ============================================================================
// ABLATION kernels (diagnostic round). Same grid/skeleton as kbig:
//  512 blocks x 256 thr, 8 tile-steps, 1 BARL/tile, 256KB clw-class reads/blk.
//  V=0: LINEAR contiguous stream -> reg sum            (pure-stream cost)
//  V=1: R8 SCATTERED stream -> reg sum                 (+ scatter penalty)
//  V=2: V1 + swizzled bf16 LDS staging                 (+ staging cost)
//  V=3: V2 + ds_read/pack + 32 MFMA per tile           (+ compute cost)
//  Dump-writes keep everything live (rule #17); dump area = F_PART, which
//  the real kbig fully overwrites afterwards.
// ============================================================================
template<int V>
__global__ void __launch_bounds__(256, 2) kabl(
    const float* __restrict__ clw, float* __restrict__ dump)
{
  extern __shared__ char smem[];
  const int t = threadIdx.x;
  const int rem = blockIdx.x & 255;
  const int mt = rem >> 5, s = rem & 31;
  const int n0 = s * 8, m0g = mt * 32;
  const int lane = t & 63, w = t >> 6;
  const int l15 = lane & 15, lhi = lane >> 4;
  const int swz = (l15 & 7) << 4;
  const float4* clwf4 = (const float4*)clw;
  const size_t base4 = (size_t)rem * 16384;  // linear 256KB chunk (in float4)

  float4 acc = {0.f, 0.f, 0.f, 0.f};
  f32x4 h0 = {0.f,0.f,0.f,0.f}, h1 = h0, h2 = h0, h3 = h0;
  bf16x8 afd0, afd1;
#pragma unroll
  for (int i = 0; i < 8; ++i) {
    afd0[i] = (__bf16)(float)(lane + i);
    afd1[i] = (__bf16)(float)(lane - i);
  }

#pragma unroll
  for (int TT = 0; TT < 8; ++TT) {
    float4 r[8];
    if constexpr (V == 0) {
#pragma unroll
      for (int i = 0; i < 8; ++i)
        r[i] = clwf4[base4 + (size_t)TT * 2048 + i * 256 + t];
    } else {
#pragma unroll
      for (int i = 0; i < 8; ++i)
        r[i] = clwf4[(size_t)((m0g + w * 8 + i) * 256 + n0 + TT) * 64 + lane];
    }
    if constexpr (V <= 1) {
#pragma unroll
      for (int i = 0; i < 8; ++i) {
        acc.x += r[i].x; acc.y += r[i].y; acc.z += r[i].z; acc.w += r[i].w;
      }
      BARL();
    } else {
#pragma unroll
      for (int i = 0; i < 8; ++i) {
        const int rowl = w * 8 + i;
        *(bf16x4v*)(smem + (TT & 1) * 16384 + rowl * 512 +
                    ((lane * 8) ^ ((rowl & 7) << 4))) = pack4(r[i]);
      }
      BARL();
      if constexpr (V >= 3) {
        const char* buf = smem + (TT & 1) * 16384;
#pragma unroll
        for (int c = 0; c < 8; ++c) {
          const int kb = c * 64 + lhi * 16;
          bf16x8 b0 = *(const bf16x8*)(buf + l15 * 512 + (kb ^ swz));
          bf16x8 b1 = *(const bf16x8*)(buf + (16 + l15) * 512 + (kb ^ swz));
          h0 = mfma16(afd0, b0, h0);
          h1 = mfma16(afd0, b1, h1);
          h2 = mfma16(afd1, b0, h2);
          h3 = mfma16(afd1, b1, h3);
        }
      }
    }
  }
  if constexpr (V == 2) {  // staged-but-unread liveness
    float4 lv = *(const float4*)(smem + t * 64);
    acc.x += lv.x; acc.y += lv.y; acc.z += lv.z; acc.w += lv.w;
  }
  float4 o = acc;
  o.x += h0[0] + h1[1] + h2[2] + h3[3];
  o.y += h0[1] + h1[2] + h2[3] + h3[0];
  ((float4*)dump)[(size_t)blockIdx.x * 256 + t] = o;
}

// ============================================================================
// kbig v8 (REAL, unchanged from R8): grid 512, 256 thr, depth-2 reg prefetch,
// 3 rotating bf16 LDS bufs, 1 barrier/tile.
// ============================================================================
__global__ void __launch_bounds__(256, 2) kbig(
    const float* __restrict__ X, const float* __restrict__ ctx,
    const float* __restrict__ W, const float* __restrict__ clb,
    const float* __restrict__ clw, float* __restrict__ ws)
{
  extern __shared__ char smem[];
  float* xl   = (float*)(smem + 49152);
  float* sred = (float*)(smem + 53248);
  float* red  = (float*)smem;
  const int t = threadIdx.x;
  const int bh = blockIdx.x >> 8;
  const int rem = blockIdx.x & 255;
  const int mt = rem >> 5, s = rem & 31;
  const int n0 = s * 8, m0g = mt * 32, b0g = bh * 128;

  const int lane = t & 63, w = t >> 6;
  const int wb = w * 32;
  const int l15 = lane & 15, lhi = lane >> 4;
  const int swz = (l15 & 7) << 4;
  const float4* clwf4 = (const float4*)clw;

  bf16x8 af[2][8];
#pragma unroll
  for (int i = 0; i < 2; ++i)
#pragma unroll
    for (int c = 0; c < 8; ++c) {
      const float4* p = (const float4*)(ctx + (b0g + wb + i * 16 + l15) * N +
                                        c * 32 + lhi * 8);
      af[i][c] = pack8(p[0], p[1]);
    }
  if (t < 128) {
    const float4* xp = (const float4*)(X + (b0g + t) * N + n0);
    const float4 x0 = xp[0], x1 = xp[1];
    xl[0 * 128 + t] = x0.x; xl[1 * 128 + t] = x0.y;
    xl[2 * 128 + t] = x0.z; xl[3 * 128 + t] = x0.w;
    xl[4 * 128 + t] = x1.x; xl[5 * 128 + t] = x1.y;
    xl[6 * 128 + t] = x1.z; xl[7 * 128 + t] = x1.w;
  }

#define ISSUE(TT, R)                                                        \
  _Pragma("unroll")                                                         \
  for (int i = 0; i < 8; ++i) {                                             \
    const int rowl = w * 8 + i;                                             \
    R[i] = clwf4[(size_t)((m0g + rowl) * 256 + n0 + (TT)) * 64 + lane];     \
  }
#define WRITE(TT, R)                                                        \
  _Pragma("unroll")                                                         \
  for (int i = 0; i < 8; ++i) {                                             \
    const int rowl = w * 8 + i;                                             \
    *(bf16x4v*)(smem + ((TT) % 3) * 16384 + rowl * 512 +                    \
                ((lane * 8) ^ ((rowl & 7) << 4))) = pack4(R[i]);            \
  }

  float4 rA[8], rB[8];
  ISSUE(0, rA)
  ISSUE(1, rB)
  __builtin_amdgcn_sched_barrier(0);

  const f32x4 zero = {0.f, 0.f, 0.f, 0.f};
  f32x4 acc[2][2];
  acc[0][0] = zero; acc[0][1] = zero; acc[1][0] = zero; acc[1][1] = zero;

#define COMP(NNV)                                                           \
  {                                                                         \
    const char* buf = smem + ((NNV) % 3) * 16384;                           \
    f32x4 h[2][2];                                                          \
    h[0][0] = zero; h[0][1] = zero; h[1][0] = zero; h[1][1] = zero;         \
    _Pragma("unroll")                                                       \
    for (int c = 0; c < 8; ++c) {                                           \
      const int kb = c * 64 + lhi * 16;                                     \
      bf16x8 b0 = *(const bf16x8*)(buf + l15 * 512 + (kb ^ swz));           \
      bf16x8 b1 = *(const bf16x8*)(buf + (16 + l15) * 512 + (kb ^ swz));    \
      h[0][0] = mfma16(af[0][c], b0, h[0][0]);                              \
      h[0][1] = mfma16(af[0][c], b1, h[0][1]);                              \
      h[1][0] = mfma16(af[1][c], b0, h[1][0]);                              \
      h[1][1] = mfma16(af[1][c], b1, h[1][1]);                              \
    }                                                                       \
    _Pragma("unroll")                                                       \
    for (int fb = 0; fb < 2; ++fb) {                                        \
      _Pragma("unroll")                                                     \
      for (int r = 0; r < 4; ++r) {                                         \
        const int brow = wb + fb * 16 + lhi * 4 + r;                        \
        const float xv = xl[(NNV) * 128 + brow];                            \
        acc[fb][0][r] += xv * h[fb][0][r];                                  \
        acc[fb][1][r] += xv * h[fb][1][r];                                  \
        float v = h[fb][0][r] + h[fb][1][r];                                \
        v += __shfl_xor(v, 1); v += __shfl_xor(v, 2);                       \
        v += __shfl_xor(v, 4); v += __shfl_xor(v, 8);                       \
        if (l15 == 0) sred[(NNV) * 128 + brow] = v;                         \
      }                                                                     \
    }                                                                       \
  }

  WRITE(0, rA)
  BARL();
  ISSUE(2, rA) __builtin_amdgcn_sched_barrier(0); WRITE(1, rB) BARL(); COMP(0)
  ISSUE(3, rB) __builtin_amdgcn_sched_barrier(0); WRITE(2, rA) BARL(); COMP(1)
  ISSUE(4, rA) __builtin_amdgcn_sched_barrier(0); WRITE(3, rB) BARL(); COMP(2)
  ISSUE(5, rB) __builtin_amdgcn_sched_barrier(0); WRITE(4, rA) BARL(); COMP(3)
  ISSUE(6, rA) __builtin_amdgcn_sched_barrier(0); WRITE(5, rB) BARL(); COMP(4)
  ISSUE(7, rB) __builtin_amdgcn_sched_barrier(0); WRITE(6, rA) BARL(); COMP(5)
  WRITE(7, rB) BARL(); COMP(6)
  COMP(7)
#undef ISSUE
#undef WRITE
#undef COMP

  const int base = blockIdx.x * 4096;
#pragma unroll
  for (int fb = 0; fb < 2; ++fb)
#pragma unroll
    for (int fm = 0; fm < 2; ++fm)
#pragma unroll
      for (int r = 0; r < 4; ++r)
        ws[F_PART + base + (wb + fb * 16 + lhi * 4 + r) * 32 + fm * 16 + l15] =
            acc[fb][fm][r];

  {
    const int bl = wb + (lane >> 1);
    const int nh = (lane & 1) * 4;
    float4 v;
    v.x = sred[(nh + 0) * 128 + bl];
    v.y = sred[(nh + 1) * 128 + bl];
    v.z = sred[(nh + 2) * 128 + bl];
    v.w = sred[(nh + 3) * 128 + bl];
    *(float4*)(ws + F_SPART + mt * NN + (b0g + bl) * N + n0 + nh) = v;
  }

  if (mt == 0 && bh == 0) {
    __syncthreads();
    const float4* wp = (const float4*)(W + t * N + s * 8);
    const float4* cp = (const float4*)(clb + t * N + s * 8);
    const float4 a0 = wp[0], a1 = wp[1], c0 = cp[0], c1 = cp[1];
    red[0 * 256 + t] = a0.x + c0.x; red[1 * 256 + t] = a0.y + c0.y;
    red[2 * 256 + t] = a0.z + c0.z; red[3 * 256 + t] = a0.w + c0.w;
    red[4 * 256 + t] = a1.x + c1.x; red[5 * 256 + t] = a1.y + c1.y;
    red[6 * 256 + t] = a1.z + c1.z; red[7 * 256 + t] = a1.w + c1.w;
    __syncthreads();
    if (t < 64) {
      const int jj = t >> 3, seg = t & 7;
      float v = 0.f;
#pragma unroll
      for (int i = 0; i < 32; ++i) v += red[jj * 256 + seg * 32 + i];
      v += __shfl_xor(v, 1);
      v += __shfl_xor(v, 2);
      v += __shfl_xor(v, 4);
      if (seg == 0) ws[F_WSC + s * 8 + jj] = v;
    }
  }
}

__global__ void __launch_bounds__(256) kred(float* __restrict__ ws)
{
  const int o = blockIdx.x * 256 + threadIdx.x;
  const int b = o >> 8, col = o & 255;
  const int mt = col >> 5, ml = col & 31;
  const int bhh = b >> 7, bl = b & 127;
  float y = 0.f;
#pragma unroll
  for (int si = 0; si < 32; ++si)
    y += ws[F_PART + (bhh * 256 + mt * 32 + si) * 4096 + bl * 32 + ml];
  ws[F_YADJ + o] = y;
  float sv = ws[F_WSC + col];
#pragma unroll
  for (int q = 0; q < 8; ++q)
    sv += ws[F_SPART + q * NN + o];
  ws[F_SFULL + o] = sv;
}

__global__ void __launch_bounds__(256) kfin(
    const float* __restrict__ X, const float* __restrict__ ctx,
    const float* __restrict__ W, const float* __restrict__ clb,
    const float* __restrict__ A, const float* __restrict__ scale,
    const int* __restrict__ tptr, float* __restrict__ out,
    float* __restrict__ ws)
{
  extern __shared__ char smem[];
  const int t = threadIdx.x, blk = blockIdx.x;
  const int b0 = (blk >> 3) * 32, k0 = (blk & 7) * 32;
  {
    const int row = t >> 3, q = t & 7;
    const int sw = (row & 7) << 4;
    const float4* sp = (const float4*)(ws + F_SFULL + (b0 + row) * N);
    const float4* xp = (const float4*)(X + (b0 + row) * N);
    const float4* wp = (const float4*)(W + (k0 + row) * N);
    const float4* cp = (const float4*)(clb + (k0 + row) * N);
#pragma unroll
    for (int i = 0; i < 8; ++i) {
      const int f4 = q * 8 + i;
      const int off = row * 512 + ((f4 * 8) ^ sw);
      *(bf16x4v*)(smem + off) = pack4(sp[f4]);
      *(bf16x4v*)(smem + 16384 + off) = pack4(xp[f4]);
      const float4 wv = wp[f4], cv = cp[f4];
      float4 s2;
      s2.x = wv.x + cv.x; s2.y = wv.y + cv.y;
      s2.z = wv.z + cv.z; s2.w = wv.w + cv.w;
      *(bf16x4v*)(smem + 49152 + off) = pack4(s2);
    }
    const float4* ap = (const float4*)(A + t * N + k0);
    char* at = smem + 32768;
#pragma unroll
    for (int i = 0; i < 8; ++i) {
      const float4 v = ap[i];
      const int kk = i * 4;
      *(__bf16*)(at + (kk + 0) * 512 + ((t * 2) ^ (((kk + 0) & 7) << 4))) = (__bf16)v.x;
      *(__bf16*)(at + (kk + 1) * 512 + ((t * 2) ^ (((kk + 1) & 7) << 4))) = (__bf16)v.y;
      *(__bf16*)(at + (kk + 2) * 512 + ((t * 2) ^ (((kk + 2) & 7) << 4))) = (__bf16)v.z;
      *(__bf16*)(at + (kk + 3) * 512 + ((t * 2) ^ (((kk + 3) & 7) << 4))) = (__bf16)v.w;
    }
  }
  __syncthreads();
  const int lane = t & 63, w = t >> 6;
  const int l15 = lane & 15, lhi = lane >> 4;
  const int wqb = (w >> 1) * 16, wqk = (w & 1) * 16;
  const int swz = (l15 & 7) << 4;
  f32x4 accd = {0.f, 0.f, 0.f, 0.f}, accw = {0.f, 0.f, 0.f, 0.f};
#pragma unroll
  for (int c = 0; c < 8; ++c) {
    const int kb = c * 64 + lhi * 16;
    bf16x8 as  = *(const bf16x8*)(smem + (wqb + l15) * 512 + (kb ^ swz));
    bf16x8 aat = *(const bf16x8*)(smem + 32768 + (wqk + l15) * 512 + (kb ^ swz));
    bf16x8 ax  = *(const bf16x8*)(smem + 16384 + (wqb + l15) * 512 + (kb ^ swz));
    bf16x8 awc = *(const bf16x8*)(smem + 49152 + (wqk + l15) * 512 + (kb ^ swz));
    accd = mfma16(as, aat, accd);
    accw = mfma16(ax, awc, accw);
  }
  const float sc = scale[0];
  const float tf = (float)(*tptr);
  const float c1 = tf / (tf + 1.f), c2 = 1.f / (tf + 1.f);
#pragma unroll
  for (int r = 0; r < 4; ++r) {
    const int b = b0 + wqb + lhi * 4 + r, k = k0 + wqk + l15;
    const int idx = b * N + k;
    const float xv = X[idx];
    out[idx] = sc * (xv * accd[r] - accw[r] - ws[F_YADJ + idx]);
    out[NN + idx] = ctx[idx] * c1 + xv * c2;
  }
}

extern "C" void kernel_launch(void* const* d_in, const int* in_sizes, int n_in,
                              void* d_out, int out_size, void* d_ws, size_t ws_size,
                              hipStream_t stream)
{
  (void)in_sizes; (void)n_in; (void)out_size;
  const float* X     = (const float*)d_in[0];
  const float* ctx   = (const float*)d_in[1];
  const float* W     = (const float*)d_in[2];
  const float* scale = (const float*)d_in[3];
  const float* A     = (const float*)d_in[4];
  const float* clw   = (const float*)d_in[5];
  const float* clb   = (const float*)d_in[6];
  const int*   tptr  = (const int*)d_in[7];
  float* out = (float*)d_out;
  float* ws  = (float*)d_ws;

  if (ws_size < (size_t)WS_FLOATS * sizeof(float)) return;

  (void)hipFuncSetAttribute((const void*)kbig,
                            hipFuncAttributeMaxDynamicSharedMemorySize, 57344);
  (void)hipFuncSetAttribute((const void*)kfin,
                            hipFuncAttributeMaxDynamicSharedMemorySize, 65536);

  // ---- diagnostic ablation dispatches (dump -> F_PART, overwritten below) ----
  float* dump = ws + F_PART;
  kabl<0><<<512, 256, 32768, stream>>>(clw, dump);  // linear stream
  kabl<1><<<512, 256, 32768, stream>>>(clw, dump);  // scattered stream
  kabl<2><<<512, 256, 32768, stream>>>(clw, dump);  // + LDS staging
  kabl<3><<<512, 256, 32768, stream>>>(clw, dump);  // + ds_read + MFMA

  // ---- real pipeline ----
  kbig<<<512, 256, 57344, stream>>>(X, ctx, W, clb, clw, ws);
  kred<<<256, 256, 0, stream>>>(ws);
  kfin<<<64, 256, 65536, stream>>>(X, ctx, W, clb, A, scale, tptr, out, ws);
}

// Round 10
// 56.832 us; speedup vs baseline: 1.8116x; 1.8116x over previous
//
#include <hip/hip_runtime.h>

#define N 256
#define NN 65536

typedef __attribute__((ext_vector_type(8))) __bf16 bf16x8;
typedef __attribute__((ext_vector_type(4))) __bf16 bf16x4v;
typedef __attribute__((ext_vector_type(4))) float f32x4;

// ---- workspace layout (float offsets) ----
#define F_PART   0u         // [512 blocks][128 bl][32 ml] yadj partials
#define F_CSPART 2097152u   // [8 mt][256 j][256 k] colsum partials (f32)
#define F_WSC    2621440u   // [256]
#define F_CSB    2621696u   // 65536 bf16 (32768 floats): CS[j][k]
#define F_SFULL  2654464u   // [65536] f32
#define F_YADJ   2720000u   // [65536] f32
#define WS_FLOATS 2785536u

static __device__ __forceinline__ f32x4 mfma16(bf16x8 a, bf16x8 b, f32x4 c) {
  return __builtin_amdgcn_mfma_f32_16x16x32_bf16(a, b, c, 0, 0, 0);
}
static __device__ __forceinline__ bf16x4v pack4(float4 v) {
  bf16x4v r;
  r[0] = (__bf16)v.x; r[1] = (__bf16)v.y; r[2] = (__bf16)v.z; r[3] = (__bf16)v.w;
  return r;
}
static __device__ __forceinline__ bf16x8 pack8(float4 a, float4 b) {
  bf16x8 r;
  r[0] = (__bf16)a.x; r[1] = (__bf16)a.y; r[2] = (__bf16)a.z; r[3] = (__bf16)a.w;
  r[4] = (__bf16)b.x; r[5] = (__bf16)b.y; r[6] = (__bf16)b.z; r[7] = (__bf16)b.w;
  return r;
}

#define BARL()                                                            \
  asm volatile("s_waitcnt lgkmcnt(0)" ::: "memory");                      \
  __builtin_amdgcn_s_barrier();                                           \
  __builtin_amdgcn_sched_barrier(0);

// ============================================================================
// kbig v10: grid 512 = 2 bh x 8 mt x 32 s; 256 thr (4 waves x 32 b-rows).
//   Structure = kabl<3> (proven ~13us): per tile {8 loads -> LDS stage ->
//   BARL -> 16 ds_read + 32 MFMA} + ONLY the yadj fmacs. The in-loop
//   shfl_xor reduction / sred / SPART path is GONE: s_adj's m-colsum is
//   b-independent -> computed from the STAGING REGISTERS (free VALU) +
//   cross-wave LDS combine, written as CSPART[mt][n][k] (bh==0 only).
// LDS: 2 bufs x 16KB @0 | csbuf 2x4KB @32768 | xl[8][128]f32 @40960
//      (45056 B; wsc 'red' 8KB reuses buf region post-loop)
// ============================================================================
__global__ void __launch_bounds__(256) kbig(
    const float* __restrict__ X, const float* __restrict__ ctx,
    const float* __restrict__ W, const float* __restrict__ clb,
    const float* __restrict__ clw, float* __restrict__ ws)
{
  extern __shared__ char smem[];
  float* csl = (float*)(smem + 32768);
  float* xl  = (float*)(smem + 40960);
  float* red = (float*)smem;
  const int t = threadIdx.x;
  const int bh = blockIdx.x >> 8;
  const int rem = blockIdx.x & 255;
  const int mt = rem >> 5, s = rem & 31;
  const int n0 = s * 8, m0g = mt * 32, b0g = bh * 128;

  const int lane = t & 63, w = t >> 6;
  const int wb = w * 32;
  const int l15 = lane & 15, lhi = lane >> 4;
  const int swz = (l15 & 7) << 4;
  const float4* clwf4 = (const float4*)clw;

  // prologue: ctx -> af (A-frags), X -> xl
  bf16x8 af[2][8];
#pragma unroll
  for (int i = 0; i < 2; ++i)
#pragma unroll
    for (int c = 0; c < 8; ++c) {
      const float4* p = (const float4*)(ctx + (b0g + wb + i * 16 + l15) * N +
                                        c * 32 + lhi * 8);
      af[i][c] = pack8(p[0], p[1]);
    }
  if (t < 128) {
    const float4* xp = (const float4*)(X + (b0g + t) * N + n0);
    const float4 x0 = xp[0], x1 = xp[1];
    xl[0 * 128 + t] = x0.x; xl[1 * 128 + t] = x0.y;
    xl[2 * 128 + t] = x0.z; xl[3 * 128 + t] = x0.w;
    xl[4 * 128 + t] = x1.x; xl[5 * 128 + t] = x1.y;
    xl[6 * 128 + t] = x1.z; xl[7 * 128 + t] = x1.w;
  }

  const f32x4 zero = {0.f, 0.f, 0.f, 0.f};
  f32x4 acc[2][2];
  acc[0][0] = zero; acc[0][1] = zero; acc[1][0] = zero; acc[1][1] = zero;

  // STAGE: loads + reg-colsum (cs) + LDS writes + BARL
#define STAGE(TT)                                                           \
  {                                                                         \
    float4 r[8];                                                            \
    _Pragma("unroll")                                                       \
    for (int i = 0; i < 8; ++i) {                                           \
      const int rowl = w * 8 + i;                                           \
      r[i] = clwf4[(size_t)((m0g + rowl) * 256 + n0 + (TT)) * 64 + lane];   \
    }                                                                       \
    _Pragma("unroll")                                                       \
    for (int i = 0; i < 8; ++i) {                                           \
      const int rowl = w * 8 + i;                                           \
      *(bf16x4v*)(smem + ((TT) & 1) * 16384 + rowl * 512 +                  \
                  ((lane * 8) ^ ((rowl & 7) << 4))) = pack4(r[i]);          \
    }                                                                       \
    if (bh == 0) {                                                          \
      float4 cso = r[0];                                                    \
      _Pragma("unroll")                                                     \
      for (int i = 1; i < 8; ++i) {                                         \
        cso.x += r[i].x; cso.y += r[i].y;                                   \
        cso.z += r[i].z; cso.w += r[i].w;                                   \
      }                                                                     \
      *(float4*)(csl + ((TT) & 1) * 1024 + w * 256 + lane * 4) = cso;       \
    }                                                                       \
    BARL();                                                                 \
  }

#define COMP(NNV)                                                           \
  {                                                                         \
    const char* buf = smem + ((NNV) & 1) * 16384;                           \
    f32x4 h[2][2];                                                          \
    h[0][0] = zero; h[0][1] = zero; h[1][0] = zero; h[1][1] = zero;         \
    _Pragma("unroll")                                                       \
    for (int c = 0; c < 8; ++c) {                                           \
      const int kb = c * 64 + lhi * 16;                                     \
      bf16x8 b0 = *(const bf16x8*)(buf + l15 * 512 + (kb ^ swz));           \
      bf16x8 b1 = *(const bf16x8*)(buf + (16 + l15) * 512 + (kb ^ swz));    \
      h[0][0] = mfma16(af[0][c], b0, h[0][0]);                              \
      h[0][1] = mfma16(af[0][c], b1, h[0][1]);                              \
      h[1][0] = mfma16(af[1][c], b0, h[1][0]);                              \
      h[1][1] = mfma16(af[1][c], b1, h[1][1]);                              \
    }                                                                       \
    _Pragma("unroll")                                                       \
    for (int fb = 0; fb < 2; ++fb) {                                        \
      _Pragma("unroll")                                                     \
      for (int r = 0; r < 4; ++r) {                                         \
        const float xv = xl[(NNV) * 128 + wb + fb * 16 + lhi * 4 + r];      \
        acc[fb][0][r] += xv * h[fb][0][r];                                  \
        acc[fb][1][r] += xv * h[fb][1][r];                                  \
      }                                                                     \
    }                                                                       \
    if (bh == 0) {                                                          \
      const int cb = ((NNV) & 1) * 1024;                                    \
      float cv = csl[cb + t] + csl[cb + 256 + t] +                          \
                 csl[cb + 512 + t] + csl[cb + 768 + t];                     \
      ws[F_CSPART + mt * 65536u + (n0 + (NNV)) * 256 + t] = cv;             \
    }                                                                       \
  }

  STAGE(0) COMP(0)
  STAGE(1) COMP(1)
  STAGE(2) COMP(2)
  STAGE(3) COMP(3)
  STAGE(4) COMP(4)
  STAGE(5) COMP(5)
  STAGE(6) COMP(6)
  STAGE(7) COMP(7)
#undef STAGE
#undef COMP

  // yadj partials: [block][128 bl][32 ml] (coalesced)
  const int base = blockIdx.x * 4096;
#pragma unroll
  for (int fb = 0; fb < 2; ++fb)
#pragma unroll
    for (int fm = 0; fm < 2; ++fm)
#pragma unroll
      for (int r = 0; r < 4; ++r)
        ws[F_PART + base + (wb + fb * 16 + lhi * 4 + r) * 32 + fm * 16 + l15] =
            acc[fb][fm][r];

  // wsc: colsum of W+CB for 8 j-columns, by (mt==0,bh==0) blocks
  if (mt == 0 && bh == 0) {
    __syncthreads();
    const float4* wp = (const float4*)(W + t * N + s * 8);
    const float4* cp = (const float4*)(clb + t * N + s * 8);
    const float4 a0 = wp[0], a1 = wp[1], c0 = cp[0], c1 = cp[1];
    red[0 * 256 + t] = a0.x + c0.x; red[1 * 256 + t] = a0.y + c0.y;
    red[2 * 256 + t] = a0.z + c0.z; red[3 * 256 + t] = a0.w + c0.w;
    red[4 * 256 + t] = a1.x + c1.x; red[5 * 256 + t] = a1.y + c1.y;
    red[6 * 256 + t] = a1.z + c1.z; red[7 * 256 + t] = a1.w + c1.w;
    __syncthreads();
    if (t < 64) {
      const int jj = t >> 3, seg = t & 7;
      float v = 0.f;
#pragma unroll
      for (int i = 0; i < 32; ++i) v += red[jj * 256 + seg * 32 + i];
      v += __shfl_xor(v, 1);
      v += __shfl_xor(v, 2);
      v += __shfl_xor(v, 4);
      if (seg == 0) ws[F_WSC + s * 8 + jj] = v;
    }
  }
}

// ============================================================================
// kred: yadj = sum over s-chunks; CS[j][k] = sum_mt CSPART -> bf16 CSB
// ============================================================================
__global__ void __launch_bounds__(256) kred(float* __restrict__ ws)
{
  const int o = blockIdx.x * 256 + threadIdx.x;
  const int b = o >> 8, col = o & 255;
  const int mt = col >> 5, ml = col & 31;
  const int bhh = b >> 7, bl = b & 127;
  float y = 0.f;
#pragma unroll
  for (int si = 0; si < 32; ++si)
    y += ws[F_PART + (bhh * 256 + mt * 32 + si) * 4096 + bl * 32 + ml];
  ws[F_YADJ + o] = y;
  float cv = 0.f;
#pragma unroll
  for (int q = 0; q < 8; ++q)
    cv += ws[F_CSPART + q * 65536u + o];
  ((__bf16*)(ws + F_CSB))[o] = (__bf16)cv;
}

// ============================================================================
// kred2: SF[b,j] = wsc[j] + sum_k ctx[b,k]*CS[j,k]  (64 blocks, LDS-free;
//   B-frags load straight from bf16 CSB[j][k] - layout matches MFMA frag)
// ============================================================================
__global__ void __launch_bounds__(256) kred2(
    const float* __restrict__ ctx, float* __restrict__ ws)
{
  const int t = threadIdx.x, blk = blockIdx.x;
  const int b0 = (blk >> 3) * 32, j0 = (blk & 7) * 32;
  const int lane = t & 63, w = t >> 6;
  const int l15 = lane & 15, lhi = lane >> 4;
  const int wqb = (w >> 1) * 16, wqj = (w & 1) * 16;
  const char* csb = (const char*)(ws + F_CSB);

  f32x4 accq = {0.f, 0.f, 0.f, 0.f};
#pragma unroll
  for (int c = 0; c < 8; ++c) {
    const float4* p = (const float4*)(ctx + (b0 + wqb + l15) * N +
                                      c * 32 + lhi * 8);
    bf16x8 a = pack8(p[0], p[1]);
    bf16x8 b = *(const bf16x8*)(csb + (j0 + wqj + l15) * 512 +
                                c * 64 + lhi * 16);
    accq = mfma16(a, b, accq);
  }
  const int j = j0 + wqj + l15;
  const float wscv = ws[F_WSC + j];
#pragma unroll
  for (int r = 0; r < 4; ++r) {
    const int b = b0 + wqb + lhi * 4 + r;
    ws[F_SFULL + b * N + j] = accq[r] + wscv;
  }
}

// ============================================================================
// kfin: unchanged (64 blocks, 2 fused K=256 MFMA chains + epilogue)
// ============================================================================
__global__ void __launch_bounds__(256) kfin(
    const float* __restrict__ X, const float* __restrict__ ctx,
    const float* __restrict__ W, const float* __restrict__ clb,
    const float* __restrict__ A, const float* __restrict__ scale,
    const int* __restrict__ tptr, float* __restrict__ out,
    float* __restrict__ ws)
{
  extern __shared__ char smem[];
  const int t = threadIdx.x, blk = blockIdx.x;
  const int b0 = (blk >> 3) * 32, k0 = (blk & 7) * 32;
  {
    const int row = t >> 3, q = t & 7;
    const int sw = (row & 7) << 4;
    const float4* sp = (const float4*)(ws + F_SFULL + (b0 + row) * N);
    const float4* xp = (const float4*)(X + (b0 + row) * N);
    const float4* wp = (const float4*)(W + (k0 + row) * N);
    const float4* cp = (const float4*)(clb + (k0 + row) * N);
#pragma unroll
    for (int i = 0; i < 8; ++i) {
      const int f4 = q * 8 + i;
      const int off = row * 512 + ((f4 * 8) ^ sw);
      *(bf16x4v*)(smem + off) = pack4(sp[f4]);
      *(bf16x4v*)(smem + 16384 + off) = pack4(xp[f4]);
      const float4 wv = wp[f4], cv = cp[f4];
      float4 s2;
      s2.x = wv.x + cv.x; s2.y = wv.y + cv.y;
      s2.z = wv.z + cv.z; s2.w = wv.w + cv.w;
      *(bf16x4v*)(smem + 49152 + off) = pack4(s2);
    }
    const float4* ap = (const float4*)(A + t * N + k0);
    char* at = smem + 32768;
#pragma unroll
    for (int i = 0; i < 8; ++i) {
      const float4 v = ap[i];
      const int kk = i * 4;
      *(__bf16*)(at + (kk + 0) * 512 + ((t * 2) ^ (((kk + 0) & 7) << 4))) = (__bf16)v.x;
      *(__bf16*)(at + (kk + 1) * 512 + ((t * 2) ^ (((kk + 1) & 7) << 4))) = (__bf16)v.y;
      *(__bf16*)(at + (kk + 2) * 512 + ((t * 2) ^ (((kk + 2) & 7) << 4))) = (__bf16)v.z;
      *(__bf16*)(at + (kk + 3) * 512 + ((t * 2) ^ (((kk + 3) & 7) << 4))) = (__bf16)v.w;
    }
  }
  __syncthreads();
  const int lane = t & 63, w = t >> 6;
  const int l15 = lane & 15, lhi = lane >> 4;
  const int wqb = (w >> 1) * 16, wqk = (w & 1) * 16;
  const int swz = (l15 & 7) << 4;
  f32x4 accd = {0.f, 0.f, 0.f, 0.f}, accw = {0.f, 0.f, 0.f, 0.f};
#pragma unroll
  for (int c = 0; c < 8; ++c) {
    const int kb = c * 64 + lhi * 16;
    bf16x8 as  = *(const bf16x8*)(smem + (wqb + l15) * 512 + (kb ^ swz));
    bf16x8 aat = *(const bf16x8*)(smem + 32768 + (wqk + l15) * 512 + (kb ^ swz));
    bf16x8 ax  = *(const bf16x8*)(smem + 16384 + (wqb + l15) * 512 + (kb ^ swz));
    bf16x8 awc = *(const bf16x8*)(smem + 49152 + (wqk + l15) * 512 + (kb ^ swz));
    accd = mfma16(as, aat, accd);
    accw = mfma16(ax, awc, accw);
  }
  const float sc = scale[0];
  const float tf = (float)(*tptr);
  const float c1 = tf / (tf + 1.f), c2 = 1.f / (tf + 1.f);
#pragma unroll
  for (int r = 0; r < 4; ++r) {
    const int b = b0 + wqb + lhi * 4 + r, k = k0 + wqk + l15;
    const int idx = b * N + k;
    const float xv = X[idx];
    out[idx] = sc * (xv * accd[r] - accw[r] - ws[F_YADJ + idx]);
    out[NN + idx] = ctx[idx] * c1 + xv * c2;
  }
}

extern "C" void kernel_launch(void* const* d_in, const int* in_sizes, int n_in,
                              void* d_out, int out_size, void* d_ws, size_t ws_size,
                              hipStream_t stream)
{
  (void)in_sizes; (void)n_in; (void)out_size;
  const float* X     = (const float*)d_in[0];
  const float* ctx   = (const float*)d_in[1];
  const float* W     = (const float*)d_in[2];
  const float* scale = (const float*)d_in[3];
  const float* A     = (const float*)d_in[4];
  const float* clw   = (const float*)d_in[5];
  const float* clb   = (const float*)d_in[6];
  const int*   tptr  = (const int*)d_in[7];
  float* out = (float*)d_out;
  float* ws  = (float*)d_ws;

  if (ws_size < (size_t)WS_FLOATS * sizeof(float)) return;

  (void)hipFuncSetAttribute((const void*)kbig,
                            hipFuncAttributeMaxDynamicSharedMemorySize, 45056);
  (void)hipFuncSetAttribute((const void*)kfin,
                            hipFuncAttributeMaxDynamicSharedMemorySize, 65536);

  kbig<<<512, 256, 45056, stream>>>(X, ctx, W, clb, clw, ws);
  kred<<<256, 256, 0, stream>>>(ws);
  kred2<<<64, 256, 0, stream>>>(ctx, ws);
  kfin<<<64, 256, 65536, stream>>>(X, ctx, W, clb, A, scale, tptr, out, ws);
}

// Round 11
// 54.765 us; speedup vs baseline: 1.8799x; 1.0377x over previous
//
#include <hip/hip_runtime.h>

#define N 256
#define NN 65536

typedef __attribute__((ext_vector_type(8))) __bf16 bf16x8;
typedef __attribute__((ext_vector_type(4))) __bf16 bf16x4v;
typedef __attribute__((ext_vector_type(4))) float f32x4;

// ---- workspace layout (float offsets) ----
#define F_PART   0u         // [1024 blocks][64 bl][32 ml] yadj partials
#define F_CSPART 2097152u   // [8 mt][256 n][256 k] colsum partials (f32)
#define F_WSC    2621440u   // [256]
#define F_CSB    2621696u   // 65536 bf16 (32768 floats): CS[j][k]
#define F_SFULL  2654464u   // [65536] f32
#define F_YADJ   2720000u   // [65536] f32
#define WS_FLOATS 2785536u

static __device__ __forceinline__ f32x4 mfma16(bf16x8 a, bf16x8 b, f32x4 c) {
  return __builtin_amdgcn_mfma_f32_16x16x32_bf16(a, b, c, 0, 0, 0);
}
static __device__ __forceinline__ bf16x4v pack4(float4 v) {
  bf16x4v r;
  r[0] = (__bf16)v.x; r[1] = (__bf16)v.y; r[2] = (__bf16)v.z; r[3] = (__bf16)v.w;
  return r;
}
static __device__ __forceinline__ bf16x8 pack8(float4 a, float4 b) {
  bf16x8 r;
  r[0] = (__bf16)a.x; r[1] = (__bf16)a.y; r[2] = (__bf16)a.z; r[3] = (__bf16)a.w;
  r[4] = (__bf16)b.x; r[5] = (__bf16)b.y; r[6] = (__bf16)b.z; r[7] = (__bf16)b.w;
  return r;
}

#define BARL()                                                            \
  asm volatile("s_waitcnt lgkmcnt(0)" ::: "memory");                      \
  __builtin_amdgcn_s_barrier();                                           \
  __builtin_amdgcn_sched_barrier(0);

// ============================================================================
// kbig v11: LOW-VGPR variant. grid 1024 = 4 bh x 8 mt x 32 s; 256 thr
//   (4 waves x 16 b-rows => af[8] = 32 VGPRs instead of 64; target ~120
//   VGPR -> 4 waves/SIMD, LDS 42KB -> 3 blocks/CU, ~12 waves/CU).
//   Loop body = proven kabl<3> core: {8 loads -> stage -> BARL -> 16
//   ds_read + 16 MFMA} + yadj fmacs + reg-colsum CS (bh==0 only).
//   bh-twins are 256 apart in blockIdx -> SAME XCD -> clw re-reads are
//   L2/L3-served; HBM traffic stays ~64MB.
// LDS: 2 bufs x 16KB @0 | csl 2x4KB @32768 | xl[8][64]f32 @40960
//      (43008 B; wsc 'red' 8KB reuses buf region post-loop)
// ============================================================================
__global__ void __launch_bounds__(256) kbig(
    const float* __restrict__ X, const float* __restrict__ ctx,
    const float* __restrict__ W, const float* __restrict__ clb,
    const float* __restrict__ clw, float* __restrict__ ws)
{
  extern __shared__ char smem[];
  float* csl = (float*)(smem + 32768);
  float* xl  = (float*)(smem + 40960);
  float* red = (float*)smem;
  const int t = threadIdx.x;
  const int bh = blockIdx.x >> 8;          // 0..3
  const int rem = blockIdx.x & 255;
  const int mt = rem >> 5, s = rem & 31;
  const int n0 = s * 8, m0g = mt * 32, b0g = bh * 64;

  const int lane = t & 63, w = t >> 6;
  const int wb = w * 16;                   // local b-base of this wave (0..48)
  const int l15 = lane & 15, lhi = lane >> 4;
  const int swz = (l15 & 7) << 4;
  const float4* clwf4 = (const float4*)clw;

  // prologue: ctx -> af (ONE b-frag per wave: 32 VGPRs), X -> xl
  bf16x8 af[8];
#pragma unroll
  for (int c = 0; c < 8; ++c) {
    const float4* p = (const float4*)(ctx + (b0g + wb + l15) * N +
                                      c * 32 + lhi * 8);
    af[c] = pack8(p[0], p[1]);
  }
  if (t < 64) {  // xl[nn][bl] = X[b0g+bl, n0+nn]
    const float4* xp = (const float4*)(X + (b0g + t) * N + n0);
    const float4 x0 = xp[0], x1 = xp[1];
    xl[0 * 64 + t] = x0.x; xl[1 * 64 + t] = x0.y;
    xl[2 * 64 + t] = x0.z; xl[3 * 64 + t] = x0.w;
    xl[4 * 64 + t] = x1.x; xl[5 * 64 + t] = x1.y;
    xl[6 * 64 + t] = x1.z; xl[7 * 64 + t] = x1.w;
  }

  const f32x4 zero = {0.f, 0.f, 0.f, 0.f};
  f32x4 acc[2];                            // [m-frag]: 16b x 32m per wave
  acc[0] = zero; acc[1] = zero;

#define STAGE(TT)                                                           \
  {                                                                         \
    float4 r[8];                                                            \
    _Pragma("unroll")                                                       \
    for (int i = 0; i < 8; ++i) {                                           \
      const int rowl = w * 8 + i;                                           \
      r[i] = clwf4[(size_t)((m0g + rowl) * 256 + n0 + (TT)) * 64 + lane];   \
    }                                                                       \
    _Pragma("unroll")                                                       \
    for (int i = 0; i < 8; ++i) {                                           \
      const int rowl = w * 8 + i;                                           \
      *(bf16x4v*)(smem + ((TT) & 1) * 16384 + rowl * 512 +                  \
                  ((lane * 8) ^ ((rowl & 7) << 4))) = pack4(r[i]);          \
    }                                                                       \
    if (bh == 0) {                                                          \
      float4 cso = r[0];                                                    \
      _Pragma("unroll")                                                     \
      for (int i = 1; i < 8; ++i) {                                         \
        cso.x += r[i].x; cso.y += r[i].y;                                   \
        cso.z += r[i].z; cso.w += r[i].w;                                   \
      }                                                                     \
      *(float4*)(csl + ((TT) & 1) * 1024 + w * 256 + lane * 4) = cso;       \
    }                                                                       \
    BARL();                                                                 \
  }

#define COMP(NNV)                                                           \
  {                                                                         \
    const char* buf = smem + ((NNV) & 1) * 16384;                           \
    f32x4 h[2];                                                             \
    h[0] = zero; h[1] = zero;                                               \
    _Pragma("unroll")                                                       \
    for (int c = 0; c < 8; ++c) {                                           \
      const int kb = c * 64 + lhi * 16;                                     \
      bf16x8 b0 = *(const bf16x8*)(buf + l15 * 512 + (kb ^ swz));           \
      bf16x8 b1 = *(const bf16x8*)(buf + (16 + l15) * 512 + (kb ^ swz));    \
      h[0] = mfma16(af[c], b0, h[0]);                                       \
      h[1] = mfma16(af[c], b1, h[1]);                                       \
    }                                                                       \
    _Pragma("unroll")                                                       \
    for (int r = 0; r < 4; ++r) {                                           \
      const float xv = xl[(NNV) * 64 + wb + lhi * 4 + r];                   \
      acc[0][r] += xv * h[0][r];                                            \
      acc[1][r] += xv * h[1][r];                                            \
    }                                                                       \
    if (bh == 0) {                                                          \
      const int cb = ((NNV) & 1) * 1024;                                    \
      float cv = csl[cb + t] + csl[cb + 256 + t] +                          \
                 csl[cb + 512 + t] + csl[cb + 768 + t];                     \
      ws[F_CSPART + mt * 65536u + (n0 + (NNV)) * 256 + t] = cv;             \
    }                                                                       \
  }

  STAGE(0) COMP(0)
  STAGE(1) COMP(1)
  STAGE(2) COMP(2)
  STAGE(3) COMP(3)
  STAGE(4) COMP(4)
  STAGE(5) COMP(5)
  STAGE(6) COMP(6)
  STAGE(7) COMP(7)
#undef STAGE
#undef COMP

  // yadj partials: [block][64 bl][32 ml] (coalesced)
  const int base = blockIdx.x * 2048;
#pragma unroll
  for (int fm = 0; fm < 2; ++fm)
#pragma unroll
    for (int r = 0; r < 4; ++r)
      ws[F_PART + base + (wb + lhi * 4 + r) * 32 + fm * 16 + l15] =
          acc[fm][r];

  // wsc: colsum of W+CB for 8 j-columns, by (mt==0,bh==0) blocks
  if (mt == 0 && bh == 0) {
    __syncthreads();
    const float4* wp = (const float4*)(W + t * N + s * 8);
    const float4* cp = (const float4*)(clb + t * N + s * 8);
    const float4 a0 = wp[0], a1 = wp[1], c0 = cp[0], c1 = cp[1];
    red[0 * 256 + t] = a0.x + c0.x; red[1 * 256 + t] = a0.y + c0.y;
    red[2 * 256 + t] = a0.z + c0.z; red[3 * 256 + t] = a0.w + c0.w;
    red[4 * 256 + t] = a1.x + c1.x; red[5 * 256 + t] = a1.y + c1.y;
    red[6 * 256 + t] = a1.z + c1.z; red[7 * 256 + t] = a1.w + c1.w;
    __syncthreads();
    if (t < 64) {
      const int jj = t >> 3, seg = t & 7;
      float v = 0.f;
#pragma unroll
      for (int i = 0; i < 32; ++i) v += red[jj * 256 + seg * 32 + i];
      v += __shfl_xor(v, 1);
      v += __shfl_xor(v, 2);
      v += __shfl_xor(v, 4);
      if (seg == 0) ws[F_WSC + s * 8 + jj] = v;
    }
  }
}

// ============================================================================
// kred: yadj = sum over s-chunks; CS[j][k] = sum_mt CSPART -> bf16 CSB
// ============================================================================
__global__ void __launch_bounds__(256) kred(float* __restrict__ ws)
{
  const int o = blockIdx.x * 256 + threadIdx.x;
  const int b = o >> 8, col = o & 255;
  const int mt = col >> 5, ml = col & 31;
  const int bhh = b >> 6, bl = b & 63;
  float y = 0.f;
#pragma unroll
  for (int si = 0; si < 32; ++si)
    y += ws[F_PART + (size_t)(bhh * 256 + mt * 32 + si) * 2048 + bl * 32 + ml];
  ws[F_YADJ + o] = y;
  float cv = 0.f;
#pragma unroll
  for (int q = 0; q < 8; ++q)
    cv += ws[F_CSPART + q * 65536u + o];
  ((__bf16*)(ws + F_CSB))[o] = (__bf16)cv;
}

// ============================================================================
// kred2: SF[b,j] = wsc[j] + sum_k ctx[b,k]*CS[j,k]  (64 blocks, LDS-free)
// ============================================================================
__global__ void __launch_bounds__(256) kred2(
    const float* __restrict__ ctx, float* __restrict__ ws)
{
  const int t = threadIdx.x, blk = blockIdx.x;
  const int b0 = (blk >> 3) * 32, j0 = (blk & 7) * 32;
  const int lane = t & 63, w = t >> 6;
  const int l15 = lane & 15, lhi = lane >> 4;
  const int wqb = (w >> 1) * 16, wqj = (w & 1) * 16;
  const char* csb = (const char*)(ws + F_CSB);

  f32x4 accq = {0.f, 0.f, 0.f, 0.f};
#pragma unroll
  for (int c = 0; c < 8; ++c) {
    const float4* p = (const float4*)(ctx + (b0 + wqb + l15) * N +
                                      c * 32 + lhi * 8);
    bf16x8 a = pack8(p[0], p[1]);
    bf16x8 b = *(const bf16x8*)(csb + (j0 + wqj + l15) * 512 +
                                c * 64 + lhi * 16);
    accq = mfma16(a, b, accq);
  }
  const int j = j0 + wqj + l15;
  const float wscv = ws[F_WSC + j];
#pragma unroll
  for (int r = 0; r < 4; ++r) {
    const int b = b0 + wqb + lhi * 4 + r;
    ws[F_SFULL + b * N + j] = accq[r] + wscv;
  }
}

// ============================================================================
// kfin: unchanged (64 blocks, 2 fused K=256 MFMA chains + epilogue)
// ============================================================================
__global__ void __launch_bounds__(256) kfin(
    const float* __restrict__ X, const float* __restrict__ ctx,
    const float* __restrict__ W, const float* __restrict__ clb,
    const float* __restrict__ A, const float* __restrict__ scale,
    const int* __restrict__ tptr, float* __restrict__ out,
    float* __restrict__ ws)
{
  extern __shared__ char smem[];
  const int t = threadIdx.x, blk = blockIdx.x;
  const int b0 = (blk >> 3) * 32, k0 = (blk & 7) * 32;
  {
    const int row = t >> 3, q = t & 7;
    const int sw = (row & 7) << 4;
    const float4* sp = (const float4*)(ws + F_SFULL + (b0 + row) * N);
    const float4* xp = (const float4*)(X + (b0 + row) * N);
    const float4* wp = (const float4*)(W + (k0 + row) * N);
    const float4* cp = (const float4*)(clb + (k0 + row) * N);
#pragma unroll
    for (int i = 0; i < 8; ++i) {
      const int f4 = q * 8 + i;
      const int off = row * 512 + ((f4 * 8) ^ sw);
      *(bf16x4v*)(smem + off) = pack4(sp[f4]);
      *(bf16x4v*)(smem + 16384 + off) = pack4(xp[f4]);
      const float4 wv = wp[f4], cv = cp[f4];
      float4 s2;
      s2.x = wv.x + cv.x; s2.y = wv.y + cv.y;
      s2.z = wv.z + cv.z; s2.w = wv.w + cv.w;
      *(bf16x4v*)(smem + 49152 + off) = pack4(s2);
    }
    const float4* ap = (const float4*)(A + t * N + k0);
    char* at = smem + 32768;
#pragma unroll
    for (int i = 0; i < 8; ++i) {
      const float4 v = ap[i];
      const int kk = i * 4;
      *(__bf16*)(at + (kk + 0) * 512 + ((t * 2) ^ (((kk + 0) & 7) << 4))) = (__bf16)v.x;
      *(__bf16*)(at + (kk + 1) * 512 + ((t * 2) ^ (((kk + 1) & 7) << 4))) = (__bf16)v.y;
      *(__bf16*)(at + (kk + 2) * 512 + ((t * 2) ^ (((kk + 2) & 7) << 4))) = (__bf16)v.z;
      *(__bf16*)(at + (kk + 3) * 512 + ((t * 2) ^ (((kk + 3) & 7) << 4))) = (__bf16)v.w;
    }
  }
  __syncthreads();
  const int lane = t & 63, w = t >> 6;
  const int l15 = lane & 15, lhi = lane >> 4;
  const int wqb = (w >> 1) * 16, wqk = (w & 1) * 16;
  const int swz = (l15 & 7) << 4;
  f32x4 accd = {0.f, 0.f, 0.f, 0.f}, accw = {0.f, 0.f, 0.f, 0.f};
#pragma unroll
  for (int c = 0; c < 8; ++c) {
    const int kb = c * 64 + lhi * 16;
    bf16x8 as  = *(const bf16x8*)(smem + (wqb + l15) * 512 + (kb ^ swz));
    bf16x8 aat = *(const bf16x8*)(smem + 32768 + (wqk + l15) * 512 + (kb ^ swz));
    bf16x8 ax  = *(const bf16x8*)(smem + 16384 + (wqb + l15) * 512 + (kb ^ swz));
    bf16x8 awc = *(const bf16x8*)(smem + 49152 + (wqk + l15) * 512 + (kb ^ swz));
    accd = mfma16(as, aat, accd);
    accw = mfma16(ax, awc, accw);
  }
  const float sc = scale[0];
  const float tf = (float)(*tptr);
  const float c1 = tf / (tf + 1.f), c2 = 1.f / (tf + 1.f);
#pragma unroll
  for (int r = 0; r < 4; ++r) {
    const int b = b0 + wqb + lhi * 4 + r, k = k0 + wqk + l15;
    const int idx = b * N + k;
    const float xv = X[idx];
    out[idx] = sc * (xv * accd[r] - accw[r] - ws[F_YADJ + idx]);
    out[NN + idx] = ctx[idx] * c1 + xv * c2;
  }
}

extern "C" void kernel_launch(void* const* d_in, const int* in_sizes, int n_in,
                              void* d_out, int out_size, void* d_ws, size_t ws_size,
                              hipStream_t stream)
{
  (void)in_sizes; (void)n_in; (void)out_size;
  const float* X     = (const float*)d_in[0];
  const float* ctx   = (const float*)d_in[1];
  const float* W     = (const float*)d_in[2];
  const float* scale = (const float*)d_in[3];
  const float* A     = (const float*)d_in[4];
  const float* clw   = (const float*)d_in[5];
  const float* clb   = (const float*)d_in[6];
  const int*   tptr  = (const int*)d_in[7];
  float* out = (float*)d_out;
  float* ws  = (float*)d_ws;

  if (ws_size < (size_t)WS_FLOATS * sizeof(float)) return;

  (void)hipFuncSetAttribute((const void*)kbig,
                            hipFuncAttributeMaxDynamicSharedMemorySize, 43008);
  (void)hipFuncSetAttribute((const void*)kfin,
                            hipFuncAttributeMaxDynamicSharedMemorySize, 65536);

  kbig<<<1024, 256, 43008, stream>>>(X, ctx, W, clb, clw, ws);
  kred<<<256, 256, 0, stream>>>(ws);
  kred2<<<64, 256, 0, stream>>>(ctx, ws);
  kfin<<<64, 256, 65536, stream>>>(X, ctx, W, clb, A, scale, tptr, out, ws);
}